// Round 1
// baseline (1840.096 us; speedup 1.0000x reference)
//
#include <hip/hip_runtime.h>
#include <hip/hip_bf16.h>
#include <math.h>

// Problem constants
#define B_    4
#define S_    2048
#define D_    512
#define H_    8
#define DH_   64
#define E_    8
#define HID_  1365
#define CAP_  1024
#define TOK_  (B_*S_)     // 8192
#define NASS_ (B_*2*S_)   // 16384
#define RMAX_ 16896       // padded compacted-row upper bound (16384 + 8*64)

// ---------------------------------------------------------------------------
// Generic fp32 tiled GEMM, NT: C[M][N] = A[M][K] * Bt[N][K]^T + bias[n] (+resid)
// 64x64 tile, BK=16, 256 threads, 4x4 per thread.
// ---------------------------------------------------------------------------
__global__ __launch_bounds__(256) void gemm_nt(
    const float* __restrict__ A, const float* __restrict__ Bt,
    const float* __restrict__ bias, const float* __restrict__ resid,
    float* __restrict__ C, int M, int N, int K) {
  __shared__ float As[16][68];
  __shared__ float Bs[16][68];
  int m0 = blockIdx.y * 64, n0 = blockIdx.x * 64;
  int tid = threadIdx.x;
  float acc[4][4] = {};
  for (int k0 = 0; k0 < K; k0 += 16) {
#pragma unroll
    for (int p = 0; p < 4; p++) {
      int idx = tid + p * 256; int m = idx >> 4, kk = idx & 15;
      As[kk][m] = A[(size_t)(m0 + m) * K + k0 + kk];
    }
#pragma unroll
    for (int p = 0; p < 4; p++) {
      int idx = tid + p * 256; int n = idx >> 4, kk = idx & 15;
      Bs[kk][n] = Bt[(size_t)(n0 + n) * K + k0 + kk];
    }
    __syncthreads();
    int ty = tid >> 4, tx = tid & 15;
#pragma unroll
    for (int kk = 0; kk < 16; kk++) {
      float a0[4], b0[4];
#pragma unroll
      for (int i = 0; i < 4; i++) a0[i] = As[kk][ty * 4 + i];
#pragma unroll
      for (int j = 0; j < 4; j++) b0[j] = Bs[kk][tx * 4 + j];
#pragma unroll
      for (int i = 0; i < 4; i++)
#pragma unroll
        for (int j = 0; j < 4; j++) acc[i][j] += a0[i] * b0[j];
    }
    __syncthreads();
  }
  int ty = tid >> 4, tx = tid & 15;
#pragma unroll
  for (int i = 0; i < 4; i++) {
    int m = m0 + ty * 4 + i;
#pragma unroll
    for (int j = 0; j < 4; j++) {
      int n = n0 + tx * 4 + j;
      float v = acc[i][j] + bias[n];
      if (resid) v += resid[(size_t)m * N + n];
      C[(size_t)m * N + n] = v;
    }
  }
}

// ---------------------------------------------------------------------------
// Flash-style attention, fp32. Block: 32 q-rows of one (b,h). 256 thr.
// Thread t: row r = t>>3, group g = t&7 (owns 8 keys j=g+8*jj and 8 dims d=g*8+i)
// ---------------------------------------------------------------------------
__global__ __launch_bounds__(256) void attn_kernel(
    const float* __restrict__ qkv, float* __restrict__ attnb) {
  int b = blockIdx.z, h = blockIdx.y, q0 = blockIdx.x * 32;
  __shared__ float Qs[32][68], Ks[64][68], Vs[64][68], Ps[32][68];
  int tid = threadIdx.x;
#pragma unroll
  for (int p = 0; p < 8; p++) {
    int idx = tid + p * 256; int r = idx >> 6, d = idx & 63;
    Qs[r][d] = qkv[((size_t)(b * S_ + q0 + r)) * (3 * D_) + h * DH_ + d] * 0.125f;
  }
  int r = tid >> 3, g = tid & 7;
  int dbase = g * 8;
  float m = -INFINITY, l = 0.f;
  float acc[8] = {0, 0, 0, 0, 0, 0, 0, 0};
  for (int kt = 0; kt < S_ / 64; kt++) {
    __syncthreads();
#pragma unroll
    for (int p = 0; p < 16; p++) {
      int idx = tid + p * 256; int kr = idx >> 6, d = idx & 63;
      const float* pr = qkv + ((size_t)(b * S_ + kt * 64 + kr)) * (3 * D_) + h * DH_ + d;
      Ks[kr][d] = pr[D_];
      Vs[kr][d] = pr[2 * D_];
    }
    __syncthreads();
    // scores: s[jj] for keys j = g + 8*jj
    float s_[8] = {0, 0, 0, 0, 0, 0, 0, 0};
#pragma unroll
    for (int d4 = 0; d4 < 16; d4++) {
      float4 q4 = *(const float4*)&Qs[r][d4 * 4];
#pragma unroll
      for (int jj = 0; jj < 8; jj++) {
        float4 k4 = *(const float4*)&Ks[g + 8 * jj][d4 * 4];
        s_[jj] += q4.x * k4.x + q4.y * k4.y + q4.z * k4.z + q4.w * k4.w;
      }
    }
    float tmax = s_[0];
#pragma unroll
    for (int jj = 1; jj < 8; jj++) tmax = fmaxf(tmax, s_[jj]);
#pragma unroll
    for (int off = 1; off < 8; off <<= 1) tmax = fmaxf(tmax, __shfl_xor(tmax, off));
    float mnew = fmaxf(m, tmax);
    float scale = __expf(m - mnew);
    float tsum = 0.f;
#pragma unroll
    for (int jj = 0; jj < 8; jj++) { s_[jj] = __expf(s_[jj] - mnew); tsum += s_[jj]; }
#pragma unroll
    for (int off = 1; off < 8; off <<= 1) tsum += __shfl_xor(tsum, off);
    l = l * scale + tsum;
    m = mnew;
#pragma unroll
    for (int i = 0; i < 8; i++) acc[i] *= scale;
#pragma unroll
    for (int jj = 0; jj < 8; jj++) Ps[r][g + 8 * jj] = s_[jj];
    __syncthreads();
#pragma unroll 4
    for (int j = 0; j < 64; j++) {
      float pv = Ps[r][j];
      const float4* v4 = (const float4*)&Vs[j][dbase];
      float4 a = v4[0], b4 = v4[1];
      acc[0] += pv * a.x;  acc[1] += pv * a.y;  acc[2] += pv * a.z;  acc[3] += pv * a.w;
      acc[4] += pv * b4.x; acc[5] += pv * b4.y; acc[6] += pv * b4.z; acc[7] += pv * b4.w;
    }
  }
  float invl = 1.f / l;
#pragma unroll
  for (int i = 0; i < 8; i++)
    attnb[((size_t)(b * S_ + q0 + r)) * D_ + h * DH_ + dbase + i] = acc[i] * invl;
}

// ---------------------------------------------------------------------------
// Gating: logits = o2 @ Wg, softmax(8), top-2, use2; accumulate density/proxy/z.
// 256 thr = 32 tokens x 8 lanes.
// ---------------------------------------------------------------------------
__global__ __launch_bounds__(256) void gating_kernel(
    const float* __restrict__ o2, const float* __restrict__ Wg,
    int* __restrict__ e1a, int* __restrict__ e2a,
    float* __restrict__ g1a, float* __restrict__ g2a, int* __restrict__ use2a,
    float* __restrict__ dacc) {
  __shared__ float sacc[17];
  int tid = threadIdx.x;
  if (tid < 17) sacc[tid] = 0.f;
  __syncthreads();
  int tl = tid >> 3, j = tid & 7;
  int t = blockIdx.x * 32 + tl;
  const float* xr = o2 + (size_t)t * D_;
  float part[8] = {0, 0, 0, 0, 0, 0, 0, 0};
  for (int d = j; d < D_; d += 8) {
    float xv = xr[d];
    const float* wg = Wg + d * E_;
#pragma unroll
    for (int e = 0; e < 8; e++) part[e] += xv * wg[e];
  }
#pragma unroll
  for (int off = 1; off < 8; off <<= 1)
#pragma unroll
    for (int e = 0; e < 8; e++) part[e] += __shfl_xor(part[e], off);
  if (j == 0) {
    float mx = part[0];
#pragma unroll
    for (int e = 1; e < 8; e++) mx = fmaxf(mx, part[e]);
    float p[8], se = 0.f;
#pragma unroll
    for (int e = 0; e < 8; e++) { p[e] = __expf(part[e] - mx); se += p[e]; }
    float inv = 1.f / se;
#pragma unroll
    for (int e = 0; e < 8; e++) p[e] *= inv;
    float lse = logf(se) + mx;
    int a1 = 0; float m1 = p[0];
#pragma unroll
    for (int e = 1; e < 8; e++) if (p[e] > m1) { m1 = p[e]; a1 = e; }
    int a2 = -1; float m2 = -1.f;
#pragma unroll
    for (int e = 0; e < 8; e++) if (e != a1 && p[e] > m2) { m2 = p[e]; a2 = e; }
    e1a[t] = a1; e2a[t] = a2; g1a[t] = m1; g2a[t] = m2;
    use2a[t] = (m2 > 0.2f) ? 1 : 0;
    atomicAdd(&sacc[a1], 1.0f);
#pragma unroll
    for (int e = 0; e < 8; e++) atomicAdd(&sacc[8 + e], p[e]);
    atomicAdd(&sacc[16], lse * lse);
  }
  __syncthreads();
  if (tid < 17) atomicAdd(&dacc[tid], sacc[tid]);
}

// ---------------------------------------------------------------------------
// Capacity scan: exact reference cumsum semantics. One wave per batch row.
// Entry order: i<S -> top1 of token i; i>=S -> top2 of token i-S.
// ---------------------------------------------------------------------------
__global__ void scan_kernel(const int* __restrict__ e1a, const int* __restrict__ e2a,
                            const int* __restrict__ use2a,
                            int* __restrict__ posArr, int* __restrict__ kept_be) {
  int b = blockIdx.x;
  int lane = threadIdx.x;
  int cnt[8] = {0, 0, 0, 0, 0, 0, 0, 0};
  unsigned long long below = (1ull << lane) - 1ull;
  for (int it = 0; it < (2 * S_) / 64; it++) {
    int i = it * 64 + lane;
    int s = i & (S_ - 1);
    int t = b * S_ + s;
    int e, a;
    if (i < S_) { e = e1a[t]; a = 1; }
    else        { e = e2a[t]; a = use2a[t]; }
    int pos = -1;
#pragma unroll
    for (int ee = 0; ee < 8; ee++) {
      unsigned long long mask = __ballot(a && (e == ee));
      if (a && e == ee) pos = cnt[ee] + __popcll(mask & below);
      cnt[ee] += __popcll(mask);
    }
    posArr[b * (2 * S_) + i] = (a && pos < CAP_) ? pos : -1;
  }
  if (lane == 0)
    for (int ee = 0; ee < 8; ee++) kept_be[b * 8 + ee] = min(cnt[ee], CAP_);
}

// ---------------------------------------------------------------------------
// Meta: 64-aligned per-expert bases + aux-loss scalars -> d_out tail.
// ---------------------------------------------------------------------------
__global__ void finalize_meta(const int* __restrict__ kept_be,
                              int* __restrict__ ebase, int* __restrict__ bbase,
                              int* __restrict__ ecnt,
                              const float* __restrict__ dacc, float* __restrict__ outs) {
  if (threadIdx.x == 0 && blockIdx.x == 0) {
    int base = 0;
    for (int e = 0; e < 8; e++) {
      int tot = 0;
      for (int b = 0; b < 4; b++) { bbase[b * 8 + e] = tot; tot += kept_be[b * 8 + e]; }
      ecnt[e] = tot;
      ebase[e] = base;
      base += (tot + 63) & ~63;
    }
    float bal = 0.f;
    for (int e = 0; e < 8; e++) bal += (dacc[e] / (float)TOK_) * (dacc[8 + e] / (float)TOK_);
    bal *= (float)E_;
    float z = dacc[16] / (float)TOK_;
    outs[0] = 0.01f * bal + 0.001f * z;
    outs[1] = bal;
    outs[2] = z;
  }
}

// ---------------------------------------------------------------------------
// Scatter: build compacted row lists + per-token combine info.
// ---------------------------------------------------------------------------
__global__ __launch_bounds__(256) void scatter_kernel(
    const int* __restrict__ posArr, const int* __restrict__ e1a, const int* __restrict__ e2a,
    const float* __restrict__ g1a, const float* __restrict__ g2a,
    const int* __restrict__ ebase, const int* __restrict__ bbase,
    int* __restrict__ rowtok, int* __restrict__ rowexp,
    int* __restrict__ tokidx, float* __restrict__ tokw) {
  int gi = blockIdx.x * 256 + threadIdx.x;   // 0..16383
  int b = gi >> 12, i = gi & 4095;
  int k = i >> 11, s = i & (S_ - 1);
  int t = b * S_ + s;
  int pos = posArr[gi];
  int idx = -1; float w = 0.f;
  if (pos >= 0) {
    int e = k ? e2a[t] : e1a[t];
    idx = ebase[e] + bbase[b * 8 + e] + pos;
    rowtok[idx] = t;
    rowexp[idx] = e;
    w = k ? g2a[t] : g1a[t];
  }
  tokidx[k * TOK_ + t] = idx;
  tokw[k * TOK_ + t] = w;
}

// ---------------------------------------------------------------------------
// LayerNorm per compacted row. One wave per row.
// ---------------------------------------------------------------------------
__global__ __launch_bounds__(256) void ln_kernel(
    const float* __restrict__ o2, const int* __restrict__ rowtok,
    const int* __restrict__ rowexp, const float* __restrict__ ln_g,
    const float* __restrict__ ln_b, float* __restrict__ xn) {
  int row = blockIdx.x * 4 + (threadIdx.x >> 6);
  int lane = threadIdx.x & 63;
  int tok = rowtok[row];
  if (tok < 0) return;
  int e = rowexp[row];
  const float* xr = o2 + (size_t)tok * D_;
  float v[8], sum = 0.f, sq = 0.f;
#pragma unroll
  for (int j = 0; j < 8; j++) { v[j] = xr[lane * 8 + j]; sum += v[j]; sq += v[j] * v[j]; }
#pragma unroll
  for (int off = 1; off < 64; off <<= 1) { sum += __shfl_xor(sum, off); sq += __shfl_xor(sq, off); }
  float mu = sum / (float)D_;
  float var = sq / (float)D_ - mu * mu;
  float inv = rsqrtf(var + 1e-5f);
  float* xo = xn + (size_t)row * D_;
#pragma unroll
  for (int j = 0; j < 8; j++) {
    int d = lane * 8 + j;
    xo[d] = (v[j] - mu) * inv * ln_g[e * D_ + d] + ln_b[e * D_ + d];
  }
}

// ---------------------------------------------------------------------------
// FFN1: h = LeakyReLU(xn @ W1[e] + b1[e]); ragged grouped GEMM (NN), 64x64 tile.
// grid: (ceil(HID/64), RMAXROWS/64 per expert, E)
// ---------------------------------------------------------------------------
__global__ __launch_bounds__(256) void ffn1_kernel(
    const float* __restrict__ xn, const float* __restrict__ W1,
    const float* __restrict__ b1, float* __restrict__ h,
    const int* __restrict__ ebase, const int* __restrict__ ecnt) {
  int e = blockIdx.z;
  int r0 = blockIdx.y * 64;
  if (r0 >= ecnt[e]) return;
  int base = ebase[e];
  int n0 = blockIdx.x * 64;
  __shared__ float As[16][68];
  __shared__ float Bs[16][68];
  const float* A = xn + (size_t)(base + r0) * D_;
  const float* Bw = W1 + (size_t)e * D_ * HID_;
  int tid = threadIdx.x;
  float acc[4][4] = {};
  for (int k0 = 0; k0 < D_; k0 += 16) {
#pragma unroll
    for (int p = 0; p < 4; p++) {
      int idx = tid + p * 256; int m = idx >> 4, kk = idx & 15;
      As[kk][m] = A[(size_t)m * D_ + k0 + kk];
    }
#pragma unroll
    for (int p = 0; p < 4; p++) {
      int idx = tid + p * 256; int kk = idx >> 6, n = idx & 63;
      int nn = n0 + n;
      Bs[kk][n] = (nn < HID_) ? Bw[(size_t)(k0 + kk) * HID_ + nn] : 0.f;
    }
    __syncthreads();
    int ty = tid >> 4, tx = tid & 15;
#pragma unroll
    for (int kk = 0; kk < 16; kk++) {
      float a0[4], b0[4];
#pragma unroll
      for (int i = 0; i < 4; i++) a0[i] = As[kk][ty * 4 + i];
#pragma unroll
      for (int j = 0; j < 4; j++) b0[j] = Bs[kk][tx * 4 + j];
#pragma unroll
      for (int i = 0; i < 4; i++)
#pragma unroll
        for (int j = 0; j < 4; j++) acc[i][j] += a0[i] * b0[j];
    }
    __syncthreads();
  }
  int ty = tid >> 4, tx = tid & 15;
#pragma unroll
  for (int i = 0; i < 4; i++) {
#pragma unroll
    for (int j = 0; j < 4; j++) {
      int n = n0 + tx * 4 + j;
      if (n < HID_) {
        float v = acc[i][j] + b1[e * HID_ + n];
        v = (v > 0.f) ? v : 0.01f * v;
        h[(size_t)(base + r0 + ty * 4 + i) * HID_ + n] = v;
      }
    }
  }
}

// ---------------------------------------------------------------------------
// FFN2: y = h @ W2[e] + b2[e]; K=1365 (masked), N=512.
// ---------------------------------------------------------------------------
__global__ __launch_bounds__(256) void ffn2_kernel(
    const float* __restrict__ h, const float* __restrict__ W2,
    const float* __restrict__ b2, float* __restrict__ y,
    const int* __restrict__ ebase, const int* __restrict__ ecnt) {
  int e = blockIdx.z;
  int r0 = blockIdx.y * 64;
  if (r0 >= ecnt[e]) return;
  int base = ebase[e];
  int n0 = blockIdx.x * 64;
  __shared__ float As[16][68];
  __shared__ float Bs[16][68];
  const float* A = h + (size_t)(base + r0) * HID_;
  const float* Bw = W2 + (size_t)e * HID_ * D_;
  int tid = threadIdx.x;
  float acc[4][4] = {};
  for (int k0 = 0; k0 < HID_; k0 += 16) {
#pragma unroll
    for (int p = 0; p < 4; p++) {
      int idx = tid + p * 256; int m = idx >> 4, kk = idx & 15;
      As[kk][m] = (k0 + kk < HID_) ? A[(size_t)m * HID_ + k0 + kk] : 0.f;
    }
#pragma unroll
    for (int p = 0; p < 4; p++) {
      int idx = tid + p * 256; int kk = idx >> 6, n = idx & 63;
      Bs[kk][n] = (k0 + kk < HID_) ? Bw[(size_t)(k0 + kk) * D_ + n0 + n] : 0.f;
    }
    __syncthreads();
    int ty = tid >> 4, tx = tid & 15;
#pragma unroll
    for (int kk = 0; kk < 16; kk++) {
      float a0[4], b0[4];
#pragma unroll
      for (int i = 0; i < 4; i++) a0[i] = As[kk][ty * 4 + i];
#pragma unroll
      for (int j = 0; j < 4; j++) b0[j] = Bs[kk][tx * 4 + j];
#pragma unroll
      for (int i = 0; i < 4; i++)
#pragma unroll
        for (int j = 0; j < 4; j++) acc[i][j] += a0[i] * b0[j];
    }
    __syncthreads();
  }
  int ty = tid >> 4, tx = tid & 15;
#pragma unroll
  for (int i = 0; i < 4; i++)
#pragma unroll
    for (int j = 0; j < 4; j++) {
      int n = n0 + tx * 4 + j;
      y[(size_t)(base + r0 + ty * 4 + i) * D_ + n] = acc[i][j] + b2[e * D_ + n];
    }
}

// ---------------------------------------------------------------------------
// Combine: out = o2 + w1*y[idx1] + w2*y[idx2]
// ---------------------------------------------------------------------------
__global__ __launch_bounds__(256) void combine_kernel(
    const float* __restrict__ o2, const float* __restrict__ y,
    const int* __restrict__ tokidx, const float* __restrict__ tokw,
    float* __restrict__ out) {
  size_t gi = (size_t)blockIdx.x * 256 + threadIdx.x;  // over TOK_*D_
  int t = (int)(gi >> 9);
  int d = (int)(gi & (D_ - 1));
  float v = o2[gi];
  int i1 = tokidx[t], i2 = tokidx[TOK_ + t];
  if (i1 >= 0) v += tokw[t] * y[(size_t)i1 * D_ + d];
  if (i2 >= 0) v += tokw[TOK_ + t] * y[(size_t)i2 * D_ + d];
  out[gi] = v;
}

// ---------------------------------------------------------------------------
extern "C" void kernel_launch(void* const* d_in, const int* in_sizes, int n_in,
                              void* d_out, int out_size, void* d_ws, size_t ws_size,
                              hipStream_t stream) {
  const float* x    = (const float*)d_in[0];
  const float* Wqkv = (const float*)d_in[1];
  const float* bqkv = (const float*)d_in[2];
  const float* Wo   = (const float*)d_in[3];
  const float* bo   = (const float*)d_in[4];
  const float* Wg   = (const float*)d_in[5];
  const float* ln_g = (const float*)d_in[6];
  const float* ln_b = (const float*)d_in[7];
  const float* W1   = (const float*)d_in[8];
  const float* b1   = (const float*)d_in[9];
  const float* W2   = (const float*)d_in[10];
  const float* b2   = (const float*)d_in[11];
  float* out = (float*)d_out;

  char* ws = (char*)d_ws;
  size_t off = 0;
  auto alloc = [&](size_t bytes) -> void* {
    void* p = ws + off;
    off = (off + bytes + 255) & ~(size_t)255;
    return p;
  };
  float* qkv   = (float*)alloc((size_t)TOK_ * 3 * D_ * 4);   // 50.3 MB
  float* attnb = (float*)alloc((size_t)TOK_ * D_ * 4);       // 16.8 MB
  float* o2    = (float*)alloc((size_t)TOK_ * D_ * 4);       // 16.8 MB
  float* xn    = (float*)alloc((size_t)RMAX_ * D_ * 4);      // 34.6 MB
  float* hbuf  = (float*)alloc((size_t)RMAX_ * HID_ * 4);    // 92.3 MB
  float* ybuf  = (float*)alloc((size_t)RMAX_ * D_ * 4);      // 34.6 MB
  int*   e1a   = (int*)alloc(TOK_ * 4);
  int*   e2a   = (int*)alloc(TOK_ * 4);
  int*   use2a = (int*)alloc(TOK_ * 4);
  float* g1a   = (float*)alloc(TOK_ * 4);
  float* g2a   = (float*)alloc(TOK_ * 4);
  int*   posArr  = (int*)alloc(NASS_ * 4);
  int*   kept_be = (int*)alloc(32 * 4);
  int*   ebase   = (int*)alloc(8 * 4);
  int*   bbase   = (int*)alloc(32 * 4);
  int*   ecnt    = (int*)alloc(8 * 4);
  int*   rowtok  = (int*)alloc(RMAX_ * 4);
  int*   rowexp  = (int*)alloc(RMAX_ * 4);
  int*   tokidx  = (int*)alloc(NASS_ * 4);
  float* tokw    = (float*)alloc(NASS_ * 4);
  float* dacc    = (float*)alloc(32 * 4);

  hipMemsetAsync(dacc, 0, 32 * 4, stream);
  hipMemsetAsync(rowtok, 0xFF, RMAX_ * 4, stream);  // -1

  // 1. QKV projection
  gemm_nt<<<dim3(24, 128), 256, 0, stream>>>(x, Wqkv, bqkv, nullptr, qkv,
                                             TOK_, 3 * D_, D_);
  // 2. Attention
  attn_kernel<<<dim3(S_ / 32, H_, B_), 256, 0, stream>>>(qkv, attnb);
  // 3. Output projection + residual
  gemm_nt<<<dim3(8, 128), 256, 0, stream>>>(attnb, Wo, bo, x, o2, TOK_, D_, D_);
  // 4. Gating
  gating_kernel<<<TOK_ / 32, 256, 0, stream>>>(o2, Wg, e1a, e2a, g1a, g2a, use2a, dacc);
  // 5. Capacity scan (exact cumsum order)
  scan_kernel<<<B_, 64, 0, stream>>>(e1a, e2a, use2a, posArr, kept_be);
  // 6. Bases + aux-loss scalars
  finalize_meta<<<1, 64, 0, stream>>>(kept_be, ebase, bbase, ecnt, dacc,
                                      out + (size_t)TOK_ * D_);
  // 7. Build compacted lists
  scatter_kernel<<<NASS_ / 256, 256, 0, stream>>>(posArr, e1a, e2a, g1a, g2a,
                                                  ebase, bbase, rowtok, rowexp,
                                                  tokidx, tokw);
  // 8. LayerNorm rows
  ln_kernel<<<RMAX_ / 4, 256, 0, stream>>>(o2, rowtok, rowexp, ln_g, ln_b, xn);
  // 9. FFN1 (ragged grouped)
  ffn1_kernel<<<dim3((HID_ + 63) / 64, 64, E_), 256, 0, stream>>>(xn, W1, b1, hbuf,
                                                                  ebase, ecnt);
  // 10. FFN2
  ffn2_kernel<<<dim3(D_ / 64, 64, E_), 256, 0, stream>>>(hbuf, W2, b2, ybuf,
                                                         ebase, ecnt);
  // 11. Combine + residual
  combine_kernel<<<(TOK_ * D_) / 256, 256, 0, stream>>>(o2, ybuf, tokidx, tokw, out);
}